// Round 1
// baseline (520.450 us; speedup 1.0000x reference)
//
#include <hip/hip_runtime.h>
#include <hip/hip_bf16.h>

typedef __attribute__((ext_vector_type(8))) short short8;
typedef __attribute__((ext_vector_type(4))) float floatx4;

static constexpr int Hn = 16, DHn = 64, Cn = 1024;
static constexpr int Bn = 4, Tn = 2048;
static constexpr int Mtot = Bn * Tn;               // 8192
static constexpr size_t QKV_STRIDE = (size_t)Bn * Hn * Tn * DHn;  // 8388608 elems

__device__ __forceinline__ unsigned short bfbits(float f) {
    __hip_bfloat16 h = __float2bfloat16(f);
    return __builtin_bit_cast(unsigned short, h);
}

// ---------------- f32 -> bf16 convert (vectorized x4) ----------------
__global__ void conv_kernel(const float4* __restrict__ src, ushort4* __restrict__ dst, int n4) {
    int i = blockIdx.x * blockDim.x + threadIdx.x;
    if (i < n4) {
        float4 v = src[i];
        ushort4 o;
        o.x = bfbits(v.x); o.y = bfbits(v.y); o.z = bfbits(v.z); o.w = bfbits(v.w);
        dst[i] = o;
    }
}

// ---------------- transpose + convert: src [R][C] f32 -> dst [C][R] bf16, batched ----------------
__global__ void tconv_kernel(const float* __restrict__ src, __hip_bfloat16* __restrict__ dst,
                             int R, int C) {
    __shared__ float tile[32][33];
    const float* s = src + (size_t)blockIdx.z * R * C;
    __hip_bfloat16* d = dst + (size_t)blockIdx.z * R * C;
    int c0 = blockIdx.x * 32;
    int r0 = blockIdx.y * 32;
    int tx = threadIdx.x;   // 0..31
    int ty = threadIdx.y;   // 0..7
    for (int i = 0; i < 4; ++i) {
        int r = r0 + ty + i * 8;
        tile[ty + i * 8][tx] = s[(size_t)r * C + c0 + tx];
    }
    __syncthreads();
    for (int i = 0; i < 4; ++i) {
        int c = c0 + ty + i * 8;
        d[(size_t)c * R + r0 + tx] = __float2bfloat16(tile[tx][ty + i * 8]);
    }
}

// ---------------- GEMM: Y[m][n] = sum_c A[m][c] * BT[n][c]  (bf16 in, f32 acc) ----------------
// MODE 0: scatter epilogue into q/k/v [w][B,H,T,DH] bf16
// MODE 1: +bias, f32 store to out [M][1024]
template<int MODE>
__global__ __launch_bounds__(256) void gemm_kernel(
    const __hip_bfloat16* __restrict__ A,   // [M][1024]
    const __hip_bfloat16* __restrict__ BT,  // [N][1024]
    const float* __restrict__ bias,
    __hip_bfloat16* __restrict__ out_qkv,   // q base; k,v at +QKV_STRIDE
    float* __restrict__ out_f32)
{
    constexpr int K = Cn;
    __shared__ __hip_bfloat16 lA[128][40];
    __shared__ __hip_bfloat16 lB[128][40];
    const int m0 = blockIdx.x * 128;
    const int n0 = blockIdx.y * 128;
    const int tid = threadIdx.x;
    const int lane = tid & 63, wid = tid >> 6;
    const int wy = wid >> 1, wx = wid & 1;
    const int fr = lane & 15, fo = (lane >> 4) * 8;

    floatx4 acc[4][4] = {};

    const int srow = tid >> 2;         // 0..63
    const int scol = (tid & 3) * 8;    // 0,8,16,24

    for (int k0 = 0; k0 < K; k0 += 32) {
        for (int half = 0; half < 2; ++half) {
            int r = srow + half * 64;
            *(short8*)(&lA[r][scol]) = *(const short8*)(&A[(size_t)(m0 + r) * K + k0 + scol]);
            *(short8*)(&lB[r][scol]) = *(const short8*)(&BT[(size_t)(n0 + r) * K + k0 + scol]);
        }
        __syncthreads();
        short8 af[4], bf[4];
        for (int t = 0; t < 4; ++t) {
            af[t] = *(const short8*)(&lA[wy * 64 + t * 16 + fr][fo]);
            bf[t] = *(const short8*)(&lB[wx * 64 + t * 16 + fr][fo]);
        }
        for (int tm = 0; tm < 4; ++tm)
            for (int tn = 0; tn < 4; ++tn)
                acc[tm][tn] = __builtin_amdgcn_mfma_f32_16x16x32_bf16(af[tm], bf[tn], acc[tm][tn], 0, 0, 0);
        __syncthreads();
    }

    for (int tm = 0; tm < 4; ++tm) {
        int rbase = m0 + wy * 64 + tm * 16 + (lane >> 4) * 4;
        for (int tn = 0; tn < 4; ++tn) {
            int nc = n0 + wx * 64 + tn * 16 + fr;
            if (MODE == 0) {
                int w = nc >> 10, rem = nc & 1023, hh = rem >> 6, dd = rem & 63;
                for (int r = 0; r < 4; ++r) {
                    int m = rbase + r;
                    int b = m >> 11, t = m & 2047;
                    out_qkv[(size_t)w * QKV_STRIDE + (((size_t)(b * Hn + hh) * Tn + t) << 6) + dd] =
                        __float2bfloat16(acc[tm][tn][r]);
                }
            } else {
                float bs = bias[nc];
                for (int r = 0; r < 4; ++r) {
                    int m = rbase + r;
                    out_f32[(size_t)m * Cn + nc] = acc[tm][tn][r] + bs;
                }
            }
        }
    }
}

// ---------------- causal flash attention ----------------
// q,k,v: [B*H][T][DH] bf16;  ao: [B][T][H*DH] bf16
__global__ __launch_bounds__(256) void attn_kernel(
    const __hip_bfloat16* __restrict__ q,
    const __hip_bfloat16* __restrict__ k,
    const __hip_bfloat16* __restrict__ v,
    __hip_bfloat16* __restrict__ ao)
{
    __shared__ __hip_bfloat16 lK[32][72];       // [s][d], padded
    __shared__ __hip_bfloat16 lV[64][40];       // transposed: [d][s], padded
    __shared__ __hip_bfloat16 lP[4][16][40];    // per-wave P [t][s], padded

    const int bh = blockIdx.y, b = bh >> 4, h = bh & 15;
    const int qb0 = blockIdx.x * 64;
    const int tid = threadIdx.x, lane = tid & 63, wid = tid >> 6;
    const int q0 = qb0 + wid * 16;
    const int fr = lane & 15, fo = (lane >> 4) * 8;
    const size_t base = (size_t)bh * Tn * DHn;

    short8 aq[2];
    aq[0] = *(const short8*)(&q[base + (size_t)(q0 + fr) * DHn + fo]);
    aq[1] = *(const short8*)(&q[base + (size_t)(q0 + fr) * DHn + fo + 32]);

    float m_r[4] = {-1e30f, -1e30f, -1e30f, -1e30f};
    float l_r[4] = {0.f, 0.f, 0.f, 0.f};
    floatx4 o[4] = {};

    const int nkv = (qb0 + 64) / 32;
    for (int j = 0; j < nkv; ++j) {
        const int kv0 = j * 32;
        {
            int r = tid >> 3, c8 = (tid & 7) * 8;
            *(short8*)(&lK[r][c8]) = *(const short8*)(&k[base + (size_t)(kv0 + r) * DHn + c8]);
            short8 vv = *(const short8*)(&v[base + (size_t)(kv0 + r) * DHn + c8]);
            const __hip_bfloat16* vp = (const __hip_bfloat16*)&vv;
            for (int jj = 0; jj < 8; ++jj)
                lV[c8 + jj][r] = vp[jj];
        }
        __syncthreads();

        if (kv0 <= q0 + 15) {
            floatx4 s[2] = {};
            for (int sh = 0; sh < 2; ++sh) {
                short8 bk0 = *(const short8*)(&lK[sh * 16 + fr][fo]);
                short8 bk1 = *(const short8*)(&lK[sh * 16 + fr][fo + 32]);
                s[sh] = __builtin_amdgcn_mfma_f32_16x16x32_bf16(aq[0], bk0, s[sh], 0, 0, 0);
                s[sh] = __builtin_amdgcn_mfma_f32_16x16x32_bf16(aq[1], bk1, s[sh], 0, 0, 0);
            }
            // scale + causal mask
            for (int sh = 0; sh < 2; ++sh) {
                int sg = kv0 + sh * 16 + fr;
                for (int r = 0; r < 4; ++r) {
                    int tg = q0 + (lane >> 4) * 4 + r;
                    float val = s[sh][r] * 0.125f;
                    s[sh][r] = (sg <= tg) ? val : -1e30f;
                }
            }
            // online softmax update (per owned row r)
            for (int r = 0; r < 4; ++r) {
                float mx = fmaxf(s[0][r], s[1][r]);
                for (int off = 1; off < 16; off <<= 1) mx = fmaxf(mx, __shfl_xor(mx, off));
                float nm = fmaxf(m_r[r], mx);
                float alpha = __expf(m_r[r] - nm);
                float p0 = __expf(s[0][r] - nm);
                float p1 = __expf(s[1][r] - nm);
                s[0][r] = p0; s[1][r] = p1;
                float rs = p0 + p1;
                for (int off = 1; off < 16; off <<= 1) rs += __shfl_xor(rs, off);
                l_r[r] = alpha * l_r[r] + rs;
                m_r[r] = nm;
                for (int td = 0; td < 4; ++td) o[td][r] *= alpha;
            }
            // P -> LDS (re-layout for MFMA A-fragment)
            for (int sh = 0; sh < 2; ++sh)
                for (int r = 0; r < 4; ++r)
                    lP[wid][(lane >> 4) * 4 + r][sh * 16 + fr] = __float2bfloat16(s[sh][r]);
            asm volatile("s_waitcnt lgkmcnt(0)" ::: "memory");
            short8 pa = *(const short8*)(&lP[wid][fr][fo]);
            for (int td = 0; td < 4; ++td) {
                short8 bv = *(const short8*)(&lV[td * 16 + fr][fo]);
                o[td] = __builtin_amdgcn_mfma_f32_16x16x32_bf16(pa, bv, o[td], 0, 0, 0);
            }
        }
        __syncthreads();
    }

    for (int td = 0; td < 4; ++td)
        for (int r = 0; r < 4; ++r) {
            int tg = q0 + (lane >> 4) * 4 + r;
            float val = o[td][r] / l_r[r];
            ao[((size_t)(b * Tn + tg)) * Cn + h * DHn + td * 16 + fr] = __float2bfloat16(val);
        }
}

extern "C" void kernel_launch(void* const* d_in, const int* in_sizes, int n_in,
                              void* d_out, int out_size, void* d_ws, size_t ws_size,
                              hipStream_t stream) {
    const float* x  = (const float*)d_in[0];
    const float* Wq = (const float*)d_in[1];
    const float* Wk = (const float*)d_in[2];
    const float* Wv = (const float*)d_in[3];
    const float* Wo = (const float*)d_in[4];
    const float* bo = (const float*)d_in[5];
    float* out = (float*)d_out;

    char* ws = (char*)d_ws;
    __hip_bfloat16* xb  = (__hip_bfloat16*)(ws);                    // [8192][1024]        16 MB
    __hip_bfloat16* wT  = (__hip_bfloat16*)(ws + 16777216);         // [3][1024][1024]      6 MB
    __hip_bfloat16* woT = (__hip_bfloat16*)(ws + 23068672);         // [1024][1024]         2 MB
    __hip_bfloat16* qb  = (__hip_bfloat16*)(ws + 25165824);         // q,k,v each 16 MB
    __hip_bfloat16* ao  = (__hip_bfloat16*)(ws + 75497472);         // [8192][1024]        16 MB

    // x -> bf16
    conv_kernel<<<(Mtot * Cn / 4 + 255) / 256, 256, 0, stream>>>(
        (const float4*)x, (ushort4*)xb, Mtot * Cn / 4);
    // weights -> transposed bf16
    tconv_kernel<<<dim3(2, 32, 16), dim3(32, 8), 0, stream>>>(Wq, wT + 0 * 1048576, Cn, DHn);
    tconv_kernel<<<dim3(2, 32, 16), dim3(32, 8), 0, stream>>>(Wk, wT + 1 * 1048576, Cn, DHn);
    tconv_kernel<<<dim3(2, 32, 16), dim3(32, 8), 0, stream>>>(Wv, wT + 2 * 1048576, Cn, DHn);
    tconv_kernel<<<dim3(32, 32, 1), dim3(32, 8), 0, stream>>>(Wo, woT, Cn, Cn);

    // QKV projection: M=8192, N=3072
    gemm_kernel<0><<<dim3(Mtot / 128, 3072 / 128), 256, 0, stream>>>(
        xb, wT, nullptr, qb, nullptr);

    // causal flash attention
    attn_kernel<<<dim3(Tn / 64, Bn * Hn), 256, 0, stream>>>(
        qb, qb + QKV_STRIDE, qb + 2 * QKV_STRIDE, ao);

    // output projection: M=8192, N=1024, +bias, f32 out
    gemm_kernel<1><<<dim3(Mtot / 128, Cn / 128), 256, 0, stream>>>(
        ao, woT, bo, nullptr, out);
}

// Round 2
// 313.332 us; speedup vs baseline: 1.6610x; 1.6610x over previous
//
#include <hip/hip_runtime.h>
#include <hip/hip_bf16.h>

typedef __attribute__((ext_vector_type(8))) short short8;
typedef __attribute__((ext_vector_type(4))) float floatx4;

static constexpr int Hn = 16, DHn = 64, Cn = 1024;
static constexpr int Bn = 4, Tn = 2048;
static constexpr int Mtot = Bn * Tn;               // 8192
static constexpr size_t QKV_STRIDE = (size_t)Bn * Hn * Tn * DHn;  // 8388608 elems

__device__ __forceinline__ unsigned short bfbits(float f) {
    __hip_bfloat16 h = __float2bfloat16(f);
    return __builtin_bit_cast(unsigned short, h);
}

// ---------------- f32 -> bf16 convert (vectorized x4) ----------------
__global__ void conv_kernel(const float4* __restrict__ src, ushort4* __restrict__ dst, int n4) {
    int i = blockIdx.x * blockDim.x + threadIdx.x;
    if (i < n4) {
        float4 v = src[i];
        ushort4 o;
        o.x = bfbits(v.x); o.y = bfbits(v.y); o.z = bfbits(v.z); o.w = bfbits(v.w);
        dst[i] = o;
    }
}

// ---------------- transpose + convert (+scale): src [R][C] f32 -> dst [C][R] bf16, batched ----------------
__global__ void tconv_kernel(const float* __restrict__ src, __hip_bfloat16* __restrict__ dst,
                             int R, int C, float scale) {
    __shared__ float tile[32][33];
    const float* s = src + (size_t)blockIdx.z * R * C;
    __hip_bfloat16* d = dst + (size_t)blockIdx.z * R * C;
    int c0 = blockIdx.x * 32;
    int r0 = blockIdx.y * 32;
    int tx = threadIdx.x;   // 0..31
    int ty = threadIdx.y;   // 0..7
    for (int i = 0; i < 4; ++i) {
        int r = r0 + ty + i * 8;
        tile[ty + i * 8][tx] = s[(size_t)r * C + c0 + tx];
    }
    __syncthreads();
    for (int i = 0; i < 4; ++i) {
        int c = c0 + ty + i * 8;
        d[(size_t)c * R + r0 + tx] = __float2bfloat16(tile[tx][ty + i * 8] * scale);
    }
}

// ---------------- GEMM: Y[m][n] = sum_c A[m][c] * BT[n][c]  (bf16 in, f32 acc) ----------------
// MODE 0: scatter epilogue into q/k [B,H,T,DH] and v TRANSPOSED [B,H,DH,T] bf16
// MODE 1: +bias, f32 store to out [M][1024]
template<int MODE>
__global__ __launch_bounds__(256) void gemm_kernel(
    const __hip_bfloat16* __restrict__ A,   // [M][1024]
    const __hip_bfloat16* __restrict__ BT,  // [N][1024]
    const float* __restrict__ bias,
    __hip_bfloat16* __restrict__ out_qkv,   // q base; k,v at +QKV_STRIDE
    float* __restrict__ out_f32)
{
    constexpr int K = Cn;
    __shared__ __hip_bfloat16 lA[128][40];
    __shared__ __hip_bfloat16 lB[128][40];
    const int m0 = blockIdx.x * 128;
    const int n0 = blockIdx.y * 128;
    const int tid = threadIdx.x;
    const int lane = tid & 63, wid = tid >> 6;
    const int wy = wid >> 1, wx = wid & 1;
    const int fr = lane & 15, fo = (lane >> 4) * 8;

    floatx4 acc[4][4] = {};

    const int srow = tid >> 2;         // 0..63
    const int scol = (tid & 3) * 8;    // 0,8,16,24

    for (int k0 = 0; k0 < K; k0 += 32) {
        for (int half = 0; half < 2; ++half) {
            int r = srow + half * 64;
            *(short8*)(&lA[r][scol]) = *(const short8*)(&A[(size_t)(m0 + r) * K + k0 + scol]);
            *(short8*)(&lB[r][scol]) = *(const short8*)(&BT[(size_t)(n0 + r) * K + k0 + scol]);
        }
        __syncthreads();
        short8 af[4], bf[4];
        for (int t = 0; t < 4; ++t) {
            af[t] = *(const short8*)(&lA[wy * 64 + t * 16 + fr][fo]);
            bf[t] = *(const short8*)(&lB[wx * 64 + t * 16 + fr][fo]);
        }
        for (int tm = 0; tm < 4; ++tm)
            for (int tn = 0; tn < 4; ++tn)
                acc[tm][tn] = __builtin_amdgcn_mfma_f32_16x16x32_bf16(af[tm], bf[tn], acc[tm][tn], 0, 0, 0);
        __syncthreads();
    }

    for (int tm = 0; tm < 4; ++tm) {
        int rbase = m0 + wy * 64 + tm * 16 + (lane >> 4) * 4;
        for (int tn = 0; tn < 4; ++tn) {
            int nc = n0 + wx * 64 + tn * 16 + fr;
            if (MODE == 0) {
                int w = nc >> 10, rem = nc & 1023, hh = rem >> 6, dd = rem & 63;
                if (w == 2) {
                    // V stored transposed: [b][h][d][t], 4 consecutive t -> vector store
                    int b = rbase >> 11, t0 = rbase & 2047;
                    ushort4 pk;
                    pk.x = bfbits(acc[tm][tn][0]);
                    pk.y = bfbits(acc[tm][tn][1]);
                    pk.z = bfbits(acc[tm][tn][2]);
                    pk.w = bfbits(acc[tm][tn][3]);
                    *(ushort4*)(&out_qkv[2 * QKV_STRIDE +
                        ((size_t)((b * Hn + hh) * DHn + dd)) * Tn + t0]) = pk;
                } else {
                    for (int r = 0; r < 4; ++r) {
                        int m = rbase + r;
                        int b = m >> 11, t = m & 2047;
                        out_qkv[(size_t)w * QKV_STRIDE + (((size_t)(b * Hn + hh) * Tn + t) << 6) + dd] =
                            __float2bfloat16(acc[tm][tn][r]);
                    }
                }
            } else {
                float bs = bias[nc];
                for (int r = 0; r < 4; ++r) {
                    int m = rbase + r;
                    out_f32[(size_t)m * Cn + nc] = acc[tm][tn][r] + bs;
                }
            }
        }
    }
}

// ---------------- causal flash attention v2 ----------------
// q,k: [B*H][T][DH] bf16;  vt: [B*H][DH][T] bf16;  ao: [B][T][H*DH] bf16
// QBLK=128 (4 waves x 32 rows), KVBLK=64, double-buffered K/V LDS, reg prefetch.
__global__ __launch_bounds__(256) void attn_kernel(
    const __hip_bfloat16* __restrict__ q,
    const __hip_bfloat16* __restrict__ k,
    const __hip_bfloat16* __restrict__ vt,
    __hip_bfloat16* __restrict__ ao)
{
    __shared__ __hip_bfloat16 lK[2][64][72];   // K row-major [s][d]
    __shared__ __hip_bfloat16 lV[2][64][72];   // V^T [d][s]
    __shared__ __hip_bfloat16 lP[4][32][72];   // per-wave P [t][s]

    const int bh = blockIdx.y, b = bh >> 4, h = bh & 15;
    const int qb0 = (gridDim.x - 1 - blockIdx.x) * 128;   // big blocks first
    const int tid = threadIdx.x, lane = tid & 63, wid = tid >> 6;
    const int q0 = qb0 + wid * 32;
    const int fr = lane & 15, g = lane >> 4, fo = g * 8;
    const size_t kbase = (size_t)bh * Tn * DHn;

    // Q fragments (1/sqrt(DH) folded into Wq at convert time)
    short8 aq[2][2];
#pragma unroll
    for (int rg = 0; rg < 2; ++rg)
#pragma unroll
        for (int kk = 0; kk < 2; ++kk)
            aq[rg][kk] = *(const short8*)(&q[kbase + (size_t)(q0 + rg * 16 + fr) * DHn + kk * 32 + fo]);

    float m_r[2][4], l_r[2][4];
    floatx4 o[2][4] = {};
#pragma unroll
    for (int rg = 0; rg < 2; ++rg)
#pragma unroll
        for (int r = 0; r < 4; ++r) { m_r[rg][r] = -1e30f; l_r[rg][r] = 0.f; }

    short8 ones;
#pragma unroll
    for (int i = 0; i < 8; ++i) ones[i] = (short)0x3F80;  // bf16 1.0

    const int nkv = qb0 / 64 + 2;
    const int srow = tid >> 3, scol = (tid & 7) * 8;      // staging: 2 chunks/thread

    short8 rk0, rk1, rv0, rv1;
    // prologue: stage tile 0
    rk0 = *(const short8*)(&k[kbase + (size_t)srow * DHn + scol]);
    rv0 = *(const short8*)(&vt[kbase + (size_t)srow * Tn + scol]);
    rk1 = *(const short8*)(&k[kbase + (size_t)(32 + srow) * DHn + scol]);
    rv1 = *(const short8*)(&vt[kbase + (size_t)(32 + srow) * Tn + scol]);
    *(short8*)(&lK[0][srow][scol]) = rk0;
    *(short8*)(&lV[0][srow][scol]) = rv0;
    *(short8*)(&lK[0][32 + srow][scol]) = rk1;
    *(short8*)(&lV[0][32 + srow][scol]) = rv1;
    __syncthreads();

    for (int j = 0; j < nkv; ++j) {
        const int kv0 = j * 64;
        const int cur = j & 1;
        const bool pf = (j + 1 < nkv);
        if (pf) {
            const int nv0 = kv0 + 64;
            rk0 = *(const short8*)(&k[kbase + (size_t)(nv0 + srow) * DHn + scol]);
            rv0 = *(const short8*)(&vt[kbase + (size_t)srow * Tn + nv0 + scol]);
            rk1 = *(const short8*)(&k[kbase + (size_t)(nv0 + 32 + srow) * DHn + scol]);
            rv1 = *(const short8*)(&vt[kbase + (size_t)(32 + srow) * Tn + nv0 + scol]);
        }

        if (kv0 < q0 + 32) {
            // ---- QK^T ----
            floatx4 s[2][4] = {};
#pragma unroll
            for (int cg = 0; cg < 4; ++cg) {
                short8 bk0 = *(const short8*)(&lK[cur][cg * 16 + fr][fo]);
                short8 bk1 = *(const short8*)(&lK[cur][cg * 16 + fr][32 + fo]);
#pragma unroll
                for (int rg = 0; rg < 2; ++rg) {
                    s[rg][cg] = __builtin_amdgcn_mfma_f32_16x16x32_bf16(aq[rg][0], bk0, s[rg][cg], 0, 0, 0);
                    s[rg][cg] = __builtin_amdgcn_mfma_f32_16x16x32_bf16(aq[rg][1], bk1, s[rg][cg], 0, 0, 0);
                }
            }
            // ---- causal mask (diagonal tiles only) ----
            if (kv0 + 64 > q0) {
#pragma unroll
                for (int rg = 0; rg < 2; ++rg)
#pragma unroll
                    for (int cg = 0; cg < 4; ++cg) {
                        int sg = kv0 + cg * 16 + fr;
#pragma unroll
                        for (int r = 0; r < 4; ++r) {
                            int tg = q0 + rg * 16 + g * 4 + r;
                            if (sg > tg) s[rg][cg][r] = -1e30f;
                        }
                    }
            }
            // ---- online softmax (max via shfl; sum via ones-MFMA below) ----
#pragma unroll
            for (int rg = 0; rg < 2; ++rg)
#pragma unroll
                for (int r = 0; r < 4; ++r) {
                    float mx = fmaxf(fmaxf(s[rg][0][r], s[rg][1][r]),
                                     fmaxf(s[rg][2][r], s[rg][3][r]));
#pragma unroll
                    for (int off = 1; off < 16; off <<= 1) mx = fmaxf(mx, __shfl_xor(mx, off));
                    float nm = fmaxf(m_r[rg][r], mx);
                    float al = __expf(m_r[rg][r] - nm);
                    m_r[rg][r] = nm;
                    l_r[rg][r] *= al;
#pragma unroll
                    for (int cg = 0; cg < 4; ++cg) s[rg][cg][r] = __expf(s[rg][cg][r] - nm);
#pragma unroll
                    for (int dg = 0; dg < 4; ++dg) o[rg][dg][r] *= al;
                }
            // ---- P -> LDS (per-wave region) ----
#pragma unroll
            for (int rg = 0; rg < 2; ++rg)
#pragma unroll
                for (int cg = 0; cg < 4; ++cg)
#pragma unroll
                    for (int r = 0; r < 4; ++r)
                        lP[wid][rg * 16 + g * 4 + r][cg * 16 + fr] = __float2bfloat16(s[rg][cg][r]);
            short8 pa[2][2];
#pragma unroll
            for (int rg = 0; rg < 2; ++rg)
#pragma unroll
                for (int kc = 0; kc < 2; ++kc)
                    pa[rg][kc] = *(const short8*)(&lP[wid][rg * 16 + fr][kc * 32 + fo]);
            // ---- rowsum via ones-MFMA ----
#pragma unroll
            for (int rg = 0; rg < 2; ++rg) {
                floatx4 rs = {};
                rs = __builtin_amdgcn_mfma_f32_16x16x32_bf16(pa[rg][0], ones, rs, 0, 0, 0);
                rs = __builtin_amdgcn_mfma_f32_16x16x32_bf16(pa[rg][1], ones, rs, 0, 0, 0);
#pragma unroll
                for (int r = 0; r < 4; ++r) l_r[rg][r] += rs[r];
            }
            // ---- PV ----
#pragma unroll
            for (int dg = 0; dg < 4; ++dg) {
                short8 bv0 = *(const short8*)(&lV[cur][dg * 16 + fr][fo]);
                short8 bv1 = *(const short8*)(&lV[cur][dg * 16 + fr][32 + fo]);
#pragma unroll
                for (int rg = 0; rg < 2; ++rg) {
                    o[rg][dg] = __builtin_amdgcn_mfma_f32_16x16x32_bf16(pa[rg][0], bv0, o[rg][dg], 0, 0, 0);
                    o[rg][dg] = __builtin_amdgcn_mfma_f32_16x16x32_bf16(pa[rg][1], bv1, o[rg][dg], 0, 0, 0);
                }
            }
        }

        if (pf) {
            const int nxt = (j + 1) & 1;
            *(short8*)(&lK[nxt][srow][scol]) = rk0;
            *(short8*)(&lV[nxt][srow][scol]) = rv0;
            *(short8*)(&lK[nxt][32 + srow][scol]) = rk1;
            *(short8*)(&lV[nxt][32 + srow][scol]) = rv1;
        }
        __syncthreads();
    }

    // epilogue
#pragma unroll
    for (int rg = 0; rg < 2; ++rg)
#pragma unroll
        for (int r = 0; r < 4; ++r) {
            int tg = q0 + rg * 16 + g * 4 + r;
            float inv = 1.0f / l_r[rg][r];
#pragma unroll
            for (int dg = 0; dg < 4; ++dg)
                ao[((size_t)(b * Tn + tg)) * Cn + h * DHn + dg * 16 + fr] =
                    __float2bfloat16(o[rg][dg][r] * inv);
        }
}

extern "C" void kernel_launch(void* const* d_in, const int* in_sizes, int n_in,
                              void* d_out, int out_size, void* d_ws, size_t ws_size,
                              hipStream_t stream) {
    const float* x  = (const float*)d_in[0];
    const float* Wq = (const float*)d_in[1];
    const float* Wk = (const float*)d_in[2];
    const float* Wv = (const float*)d_in[3];
    const float* Wo = (const float*)d_in[4];
    const float* bo = (const float*)d_in[5];
    float* out = (float*)d_out;

    char* ws = (char*)d_ws;
    __hip_bfloat16* xb  = (__hip_bfloat16*)(ws);                    // [8192][1024]        16 MB
    __hip_bfloat16* wT  = (__hip_bfloat16*)(ws + 16777216);         // [3][1024][1024]      6 MB
    __hip_bfloat16* woT = (__hip_bfloat16*)(ws + 23068672);         // [1024][1024]         2 MB
    __hip_bfloat16* qb  = (__hip_bfloat16*)(ws + 25165824);         // q,k,v each 16 MB
    __hip_bfloat16* ao  = (__hip_bfloat16*)(ws + 75497472);         // [8192][1024]        16 MB

    // x -> bf16
    conv_kernel<<<(Mtot * Cn / 4 + 255) / 256, 256, 0, stream>>>(
        (const float4*)x, (ushort4*)xb, Mtot * Cn / 4);
    // weights -> transposed bf16 (Wq carries the 1/sqrt(DH) scale)
    tconv_kernel<<<dim3(2, 32, 16), dim3(32, 8), 0, stream>>>(Wq, wT + 0 * 1048576, Cn, DHn, 0.125f);
    tconv_kernel<<<dim3(2, 32, 16), dim3(32, 8), 0, stream>>>(Wk, wT + 1 * 1048576, Cn, DHn, 1.0f);
    tconv_kernel<<<dim3(2, 32, 16), dim3(32, 8), 0, stream>>>(Wv, wT + 2 * 1048576, Cn, DHn, 1.0f);
    tconv_kernel<<<dim3(32, 32, 1), dim3(32, 8), 0, stream>>>(Wo, woT, Cn, Cn, 1.0f);

    // QKV projection: M=8192, N=3072 (V stored transposed)
    gemm_kernel<0><<<dim3(Mtot / 128, 3072 / 128), 256, 0, stream>>>(
        xb, wT, nullptr, qb, nullptr);

    // causal flash attention
    attn_kernel<<<dim3(Tn / 128, Bn * Hn), 256, 0, stream>>>(
        qb, qb + QKV_STRIDE, qb + 2 * QKV_STRIDE, ao);

    // output projection: M=8192, N=1024, +bias, f32 out
    gemm_kernel<1><<<dim3(Mtot / 128, Cn / 128), 256, 0, stream>>>(
        ao, woT, bo, nullptr, out);
}

// Round 3
// 260.428 us; speedup vs baseline: 1.9984x; 1.2031x over previous
//
#include <hip/hip_runtime.h>
#include <hip/hip_bf16.h>

typedef __attribute__((ext_vector_type(8))) short short8;
typedef __attribute__((ext_vector_type(4))) short s4v;
typedef __attribute__((ext_vector_type(4))) float floatx4;

static constexpr int Hn = 16, DHn = 64, Cn = 1024;
static constexpr int Bn = 4, Tn = 2048;
static constexpr int Mtot = Bn * Tn;               // 8192
static constexpr size_t QKV_STRIDE = (size_t)Bn * Hn * Tn * DHn;  // 8388608 elems

__device__ __forceinline__ unsigned short bfbits(float f) {
    __hip_bfloat16 h = __float2bfloat16(f);
    return __builtin_bit_cast(unsigned short, h);
}

// ---------------- f32 -> bf16 convert (vectorized x4) ----------------
__global__ void conv_kernel(const float4* __restrict__ src, ushort4* __restrict__ dst, int n4) {
    int i = blockIdx.x * blockDim.x + threadIdx.x;
    if (i < n4) {
        float4 v = src[i];
        ushort4 o;
        o.x = bfbits(v.x); o.y = bfbits(v.y); o.z = bfbits(v.z); o.w = bfbits(v.w);
        dst[i] = o;
    }
}

// ---------------- transpose + convert (+scale): src [R][C] f32 -> dst [C][R] bf16, batched ----------------
__global__ void tconv_kernel(const float* __restrict__ src, __hip_bfloat16* __restrict__ dst,
                             int R, int C, float scale) {
    __shared__ float tile[32][33];
    const float* s = src + (size_t)blockIdx.z * R * C;
    __hip_bfloat16* d = dst + (size_t)blockIdx.z * R * C;
    int c0 = blockIdx.x * 32;
    int r0 = blockIdx.y * 32;
    int tx = threadIdx.x;   // 0..31
    int ty = threadIdx.y;   // 0..7
    for (int i = 0; i < 4; ++i) {
        int r = r0 + ty + i * 8;
        tile[ty + i * 8][tx] = s[(size_t)r * C + c0 + tx];
    }
    __syncthreads();
    for (int i = 0; i < 4; ++i) {
        int c = c0 + ty + i * 8;
        d[(size_t)c * R + r0 + tx] = __float2bfloat16(tile[tx][ty + i * 8] * scale);
    }
}

// ---------------- GEMM: Y[m][n] = sum_c A[m][c] * BT[n][c]  (bf16 in, f32 acc) ----------------
template<int MODE>
__global__ __launch_bounds__(256) void gemm_kernel(
    const __hip_bfloat16* __restrict__ A,   // [M][1024]
    const __hip_bfloat16* __restrict__ BT,  // [N][1024]
    const float* __restrict__ bias,
    __hip_bfloat16* __restrict__ out_qkv,   // q base; k,v at +QKV_STRIDE
    float* __restrict__ out_f32)
{
    constexpr int K = Cn;
    __shared__ __hip_bfloat16 lA[128][40];
    __shared__ __hip_bfloat16 lB[128][40];
    const int m0 = blockIdx.x * 128;
    const int n0 = blockIdx.y * 128;
    const int tid = threadIdx.x;
    const int lane = tid & 63, wid = tid >> 6;
    const int wy = wid >> 1, wx = wid & 1;
    const int fr = lane & 15, fo = (lane >> 4) * 8;

    floatx4 acc[4][4] = {};

    const int srow = tid >> 2;         // 0..63
    const int scol = (tid & 3) * 8;    // 0,8,16,24

    for (int k0 = 0; k0 < K; k0 += 32) {
        for (int half = 0; half < 2; ++half) {
            int r = srow + half * 64;
            *(short8*)(&lA[r][scol]) = *(const short8*)(&A[(size_t)(m0 + r) * K + k0 + scol]);
            *(short8*)(&lB[r][scol]) = *(const short8*)(&BT[(size_t)(n0 + r) * K + k0 + scol]);
        }
        __syncthreads();
        short8 af[4], bf[4];
        for (int t = 0; t < 4; ++t) {
            af[t] = *(const short8*)(&lA[wy * 64 + t * 16 + fr][fo]);
            bf[t] = *(const short8*)(&lB[wx * 64 + t * 16 + fr][fo]);
        }
        for (int tm = 0; tm < 4; ++tm)
            for (int tn = 0; tn < 4; ++tn)
                acc[tm][tn] = __builtin_amdgcn_mfma_f32_16x16x32_bf16(af[tm], bf[tn], acc[tm][tn], 0, 0, 0);
        __syncthreads();
    }

    for (int tm = 0; tm < 4; ++tm) {
        int rbase = m0 + wy * 64 + tm * 16 + (lane >> 4) * 4;
        for (int tn = 0; tn < 4; ++tn) {
            int nc = n0 + wx * 64 + tn * 16 + fr;
            if (MODE == 0) {
                int w = nc >> 10, rem = nc & 1023, hh = rem >> 6, dd = rem & 63;
                if (w == 2) {
                    int b = rbase >> 11, t0 = rbase & 2047;
                    ushort4 pk;
                    pk.x = bfbits(acc[tm][tn][0]);
                    pk.y = bfbits(acc[tm][tn][1]);
                    pk.z = bfbits(acc[tm][tn][2]);
                    pk.w = bfbits(acc[tm][tn][3]);
                    *(ushort4*)(&out_qkv[2 * QKV_STRIDE +
                        ((size_t)((b * Hn + hh) * DHn + dd)) * Tn + t0]) = pk;
                } else {
                    for (int r = 0; r < 4; ++r) {
                        int m = rbase + r;
                        int b = m >> 11, t = m & 2047;
                        out_qkv[(size_t)w * QKV_STRIDE + (((size_t)(b * Hn + hh) * Tn + t) << 6) + dd] =
                            __float2bfloat16(acc[tm][tn][r]);
                    }
                }
            } else {
                float bs = bias[nc];
                for (int r = 0; r < 4; ++r) {
                    int m = rbase + r;
                    out_f32[(size_t)m * Cn + nc] = acc[tm][tn][r] + bs;
                }
            }
        }
    }
}

// ---------------- causal flash attention v3: swapped-operand, lane-local softmax ----------------
// q,k: [B*H][T][DH] bf16;  vt: [B*H][DH][T] bf16;  ao: [B][T][H*DH] bf16
// QBLK=128 (4 waves x 32 rows), KVBLK=64. mfma(K,Q) -> S^T[k][q], q = lane&15.
// P never leaves registers: permuted-k slot mapping makes the PV B-fragment the
// lane's own accumulator values; V^T LDS reads use the matching permuted columns.
// XOR-swizzled LDS (byte ^= (row&7)<<4) on both store and load sides.
__global__ __launch_bounds__(256) void attn_kernel(
    const __hip_bfloat16* __restrict__ q,
    const __hip_bfloat16* __restrict__ k,
    const __hip_bfloat16* __restrict__ vt,
    __hip_bfloat16* __restrict__ ao)
{
    __shared__ __hip_bfloat16 lK[2][64][64];   // 16 KB, K tiles [s][d]
    __shared__ __hip_bfloat16 lV[2][64][64];   // 16 KB, V^T tiles [d][t]

    const int bh = blockIdx.y, b = bh >> 4, h = bh & 15;
    const int qb0 = (gridDim.x - 1 - blockIdx.x) * 128;   // big causal blocks first
    const int tid = threadIdx.x, lane = tid & 63, wid = tid >> 6;
    const int q0 = qb0 + wid * 32;
    const int fr = lane & 15, g = lane >> 4;
    const size_t base = (size_t)bh * Tn * DHn;

    // Q fragments (B-operand: col=q=lane&15, k-chunk g*8 + kk*32). scale folded into Wq.
    short8 aq[2][2];
#pragma unroll
    for (int rq = 0; rq < 2; ++rq)
#pragma unroll
        for (int kk = 0; kk < 2; ++kk)
            aq[rq][kk] = *(const short8*)(&q[base + (size_t)(q0 + rq * 16 + fr) * DHn + kk * 32 + g * 8]);

    float m_[2] = {-1e30f, -1e30f}, l_[2] = {0.f, 0.f};
    floatx4 o[2][4] = {};   // [rq][dg]: D[d][q], d = dg*16 + g*4 + r, q = lane&15

    const int nkv = qb0 / 64 + 2;
    const int srow = tid >> 3;              // 0..31
    const int sc = tid & 7;                 // 16B chunk
    const int sxor = (sc * 16) ^ ((srow & 7) << 4);
    char* const k0p = (char*)&lK[0][0][0];
    char* const v0p = (char*)&lV[0][0][0];
    const int d0 = srow * 128 + sxor;
    const int d1 = (srow + 32) * 128 + sxor;    // (srow+32)&7 == srow&7

    short8 rk0, rk1, rv0, rv1;
    rk0 = *(const short8*)(&k[base + (size_t)srow * DHn + sc * 8]);
    rk1 = *(const short8*)(&k[base + (size_t)(srow + 32) * DHn + sc * 8]);
    rv0 = *(const short8*)(&vt[base + (size_t)srow * Tn + sc * 8]);
    rv1 = *(const short8*)(&vt[base + (size_t)(srow + 32) * Tn + sc * 8]);
    *(short8*)(k0p + d0) = rk0;
    *(short8*)(k0p + d1) = rk1;
    *(short8*)(v0p + d0) = rv0;
    *(short8*)(v0p + d1) = rv1;
    __syncthreads();

    const int rxor = (fr & 7) << 4;

    for (int j = 0; j < nkv; ++j) {
        const int kv0 = j * 64;
        const int cur = j & 1;
        const char* lkc = k0p + cur * 8192;
        const char* lvc = v0p + cur * 8192;
        const bool pfch = (j + 1 < nkv);
        if (pfch) {
            const int nv0 = kv0 + 64;
            rk0 = *(const short8*)(&k[base + (size_t)(nv0 + srow) * DHn + sc * 8]);
            rk1 = *(const short8*)(&k[base + (size_t)(nv0 + srow + 32) * DHn + sc * 8]);
            rv0 = *(const short8*)(&vt[base + (size_t)srow * Tn + nv0 + sc * 8]);
            rv1 = *(const short8*)(&vt[base + (size_t)(srow + 32) * Tn + nv0 + sc * 8]);
        }

        if (kv0 < q0 + 32) {
            // ---- QK^T (swapped): s[rq][cg] = S^T tile, row k = cg*16+g*4+r, col q = fr ----
            floatx4 s[2][4] = {};
            __builtin_amdgcn_s_setprio(1);
#pragma unroll
            for (int kk = 0; kk < 2; ++kk)
#pragma unroll
                for (int cg = 0; cg < 4; ++cg) {
                    short8 kf = *(const short8*)(lkc + (cg * 16 + fr) * 128 + ((g * 16 + kk * 64) ^ rxor));
                    s[0][cg] = __builtin_amdgcn_mfma_f32_16x16x32_bf16(kf, aq[0][kk], s[0][cg], 0, 0, 0);
                    s[1][cg] = __builtin_amdgcn_mfma_f32_16x16x32_bf16(kf, aq[1][kk], s[1][cg], 0, 0, 0);
                }
            __builtin_amdgcn_s_setprio(0);

            // ---- causal mask (diagonal region only) ----
            if (kv0 + 64 > q0) {
#pragma unroll
                for (int rq = 0; rq < 2; ++rq) {
                    int qg = q0 + rq * 16 + fr;
#pragma unroll
                    for (int cg = 0; cg < 4; ++cg) {
                        int kg = kv0 + cg * 16 + g * 4;
#pragma unroll
                        for (int r = 0; r < 4; ++r)
                            if (kg + r > qg) s[rq][cg][r] = -1e30f;
                    }
                }
            }

            // ---- lane-local online softmax ----
            short8 pb[2][2];
#pragma unroll
            for (int rq = 0; rq < 2; ++rq) {
                float mx = fmaxf(
                    fmaxf(fmaxf(fmaxf(s[rq][0][0], s[rq][0][1]), fmaxf(s[rq][0][2], s[rq][0][3])),
                          fmaxf(fmaxf(s[rq][1][0], s[rq][1][1]), fmaxf(s[rq][1][2], s[rq][1][3]))),
                    fmaxf(fmaxf(fmaxf(s[rq][2][0], s[rq][2][1]), fmaxf(s[rq][2][2], s[rq][2][3])),
                          fmaxf(fmaxf(s[rq][3][0], s[rq][3][1]), fmaxf(s[rq][3][2], s[rq][3][3]))));
                mx = fmaxf(mx, __shfl_xor(mx, 16));
                mx = fmaxf(mx, __shfl_xor(mx, 32));
                float nm = fmaxf(m_[rq], mx);
                float al = __expf(m_[rq] - nm);
                m_[rq] = nm;
                float ls = 0.f;
#pragma unroll
                for (int cg = 0; cg < 4; ++cg)
#pragma unroll
                    for (int r = 0; r < 4; ++r) {
                        float p = __expf(s[rq][cg][r] - nm);
                        s[rq][cg][r] = p;
                        ls += p;
                    }
                l_[rq] = l_[rq] * al + ls;
#pragma unroll
                for (int dg = 0; dg < 4; ++dg) o[rq][dg] *= al;
                // pack P: B-frag slot j ↔ k = kt*32 + (j<4 ? 4g+j : 16+4g+(j-4)) = own acc values
#pragma unroll
                for (int kt = 0; kt < 2; ++kt) {
                    short8 pk;
#pragma unroll
                    for (int r = 0; r < 4; ++r) {
                        pk[r]     = (short)bfbits(s[rq][2 * kt][r]);
                        pk[r + 4] = (short)bfbits(s[rq][2 * kt + 1][r]);
                    }
                    pb[rq][kt] = pk;
                }
            }

            // ---- PV (swapped): o[d][q] += V^T[d][k_perm] * P[k_perm][q] ----
            __builtin_amdgcn_s_setprio(1);
#pragma unroll
            for (int kt = 0; kt < 2; ++kt)
#pragma unroll
                for (int dg = 0; dg < 4; ++dg) {
                    const int vrow = (dg * 16 + fr) * 128;
                    s4v lo = *(const s4v*)(lvc + vrow + ((kt * 64 + 8 * g) ^ rxor));
                    s4v hi = *(const s4v*)(lvc + vrow + ((kt * 64 + 32 + 8 * g) ^ rxor));
                    short8 vf;
                    vf[0] = lo[0]; vf[1] = lo[1]; vf[2] = lo[2]; vf[3] = lo[3];
                    vf[4] = hi[0]; vf[5] = hi[1]; vf[6] = hi[2]; vf[7] = hi[3];
                    o[0][dg] = __builtin_amdgcn_mfma_f32_16x16x32_bf16(vf, pb[0][kt], o[0][dg], 0, 0, 0);
                    o[1][dg] = __builtin_amdgcn_mfma_f32_16x16x32_bf16(vf, pb[1][kt], o[1][dg], 0, 0, 0);
                }
            __builtin_amdgcn_s_setprio(0);
        }

        if (pfch) {
            char* nk = k0p + (cur ^ 1) * 8192;
            char* nv = v0p + (cur ^ 1) * 8192;
            *(short8*)(nk + d0) = rk0;
            *(short8*)(nk + d1) = rk1;
            *(short8*)(nv + d0) = rv0;
            *(short8*)(nv + d1) = rv1;
        }
        __syncthreads();
    }

    // ---- epilogue: reduce l, normalize, transpose via LDS scratch, coalesced store ----
    float inv_[2];
#pragma unroll
    for (int rq = 0; rq < 2; ++rq) {
        float lv = l_[rq];
        lv += __shfl_xor(lv, 16);
        lv += __shfl_xor(lv, 32);
        inv_[rq] = 1.0f / lv;
    }
    char* myscr = k0p + wid * 4096;   // per-wave 16x64 f32 region (reuses lK)
    const int rr = lane >> 2, cc = lane & 3;
#pragma unroll
    for (int rq = 0; rq < 2; ++rq) {
#pragma unroll
        for (int dg = 0; dg < 4; ++dg)
#pragma unroll
            for (int r = 0; r < 4; ++r) {
                int d = dg * 16 + g * 4 + r;
                *(float*)(myscr + fr * 256 + ((d * 4) ^ ((fr & 7) << 4))) = o[rq][dg][r] * inv_[rq];
            }
        asm volatile("s_waitcnt lgkmcnt(0)" ::: "memory");
        float4 f0 = *(const float4*)(myscr + rr * 256 + ((cc * 64 + 0) ^ ((rr & 7) << 4)));
        float4 f1 = *(const float4*)(myscr + rr * 256 + ((cc * 64 + 16) ^ ((rr & 7) << 4)));
        float4 f2 = *(const float4*)(myscr + rr * 256 + ((cc * 64 + 32) ^ ((rr & 7) << 4)));
        float4 f3 = *(const float4*)(myscr + rr * 256 + ((cc * 64 + 48) ^ ((rr & 7) << 4)));
        short8 pk0, pk1;
        pk0[0] = (short)bfbits(f0.x); pk0[1] = (short)bfbits(f0.y);
        pk0[2] = (short)bfbits(f0.z); pk0[3] = (short)bfbits(f0.w);
        pk0[4] = (short)bfbits(f1.x); pk0[5] = (short)bfbits(f1.y);
        pk0[6] = (short)bfbits(f1.z); pk0[7] = (short)bfbits(f1.w);
        pk1[0] = (short)bfbits(f2.x); pk1[1] = (short)bfbits(f2.y);
        pk1[2] = (short)bfbits(f2.z); pk1[3] = (short)bfbits(f2.w);
        pk1[4] = (short)bfbits(f3.x); pk1[5] = (short)bfbits(f3.y);
        pk1[6] = (short)bfbits(f3.z); pk1[7] = (short)bfbits(f3.w);
        size_t orow = ((size_t)(b * Tn + q0 + rq * 16 + rr)) * Cn + h * 64 + cc * 16;
        *(short8*)(&ao[orow]) = pk0;
        *(short8*)(&ao[orow + 8]) = pk1;
        asm volatile("s_waitcnt lgkmcnt(0)" ::: "memory");
    }
}

extern "C" void kernel_launch(void* const* d_in, const int* in_sizes, int n_in,
                              void* d_out, int out_size, void* d_ws, size_t ws_size,
                              hipStream_t stream) {
    const float* x  = (const float*)d_in[0];
    const float* Wq = (const float*)d_in[1];
    const float* Wk = (const float*)d_in[2];
    const float* Wv = (const float*)d_in[3];
    const float* Wo = (const float*)d_in[4];
    const float* bo = (const float*)d_in[5];
    float* out = (float*)d_out;

    char* ws = (char*)d_ws;
    __hip_bfloat16* xb  = (__hip_bfloat16*)(ws);                    // [8192][1024]        16 MB
    __hip_bfloat16* wT  = (__hip_bfloat16*)(ws + 16777216);         // [3][1024][1024]      6 MB
    __hip_bfloat16* woT = (__hip_bfloat16*)(ws + 23068672);         // [1024][1024]         2 MB
    __hip_bfloat16* qb  = (__hip_bfloat16*)(ws + 25165824);         // q,k,v each 16 MB
    __hip_bfloat16* ao  = (__hip_bfloat16*)(ws + 75497472);         // [8192][1024]        16 MB

    // x -> bf16
    conv_kernel<<<(Mtot * Cn / 4 + 255) / 256, 256, 0, stream>>>(
        (const float4*)x, (ushort4*)xb, Mtot * Cn / 4);
    // weights -> transposed bf16 (Wq carries the 1/sqrt(DH) scale)
    tconv_kernel<<<dim3(2, 32, 16), dim3(32, 8), 0, stream>>>(Wq, wT + 0 * 1048576, Cn, DHn, 0.125f);
    tconv_kernel<<<dim3(2, 32, 16), dim3(32, 8), 0, stream>>>(Wk, wT + 1 * 1048576, Cn, DHn, 1.0f);
    tconv_kernel<<<dim3(2, 32, 16), dim3(32, 8), 0, stream>>>(Wv, wT + 2 * 1048576, Cn, DHn, 1.0f);
    tconv_kernel<<<dim3(32, 32, 1), dim3(32, 8), 0, stream>>>(Wo, woT, Cn, Cn, 1.0f);

    // QKV projection: M=8192, N=3072 (V stored transposed)
    gemm_kernel<0><<<dim3(Mtot / 128, 3072 / 128), 256, 0, stream>>>(
        xb, wT, nullptr, qb, nullptr);

    // causal flash attention
    attn_kernel<<<dim3(Tn / 128, Bn * Hn), 256, 0, stream>>>(
        qb, qb + QKV_STRIDE, qb + 2 * QKV_STRIDE, ao);

    // output projection: M=8192, N=1024, +bias, f32 out
    gemm_kernel<1><<<dim3(Mtot / 128, Cn / 128), 256, 0, stream>>>(
        ao, woT, bo, nullptr, out);
}

// Round 4
// 196.914 us; speedup vs baseline: 2.6430x; 1.3225x over previous
//
#include <hip/hip_runtime.h>
#include <hip/hip_bf16.h>

typedef __attribute__((ext_vector_type(8))) short short8;
typedef __attribute__((ext_vector_type(4))) short s4v;
typedef __attribute__((ext_vector_type(4))) float floatx4;

static constexpr int Hn = 16, DHn = 64, Cn = 1024;
static constexpr int Bn = 4, Tn = 2048;
static constexpr int Mtot = Bn * Tn;               // 8192
static constexpr size_t QKV_STRIDE = (size_t)Bn * Hn * Tn * DHn;  // 8388608 elems

__device__ __forceinline__ unsigned short bfbits(float f) {
    __hip_bfloat16 h = __float2bfloat16(f);
    return __builtin_bit_cast(unsigned short, h);
}

// ---------------- f32 -> bf16 convert (vectorized x4) ----------------
__global__ void conv_kernel(const float4* __restrict__ src, ushort4* __restrict__ dst, int n4) {
    int i = blockIdx.x * blockDim.x + threadIdx.x;
    if (i < n4) {
        float4 v = src[i];
        ushort4 o;
        o.x = bfbits(v.x); o.y = bfbits(v.y); o.z = bfbits(v.z); o.w = bfbits(v.w);
        dst[i] = o;
    }
}

// ---------------- transpose + convert (+scale): src [R][C] f32 -> dst [C][R] bf16, batched ----------------
__global__ void tconv_kernel(const float* __restrict__ src, __hip_bfloat16* __restrict__ dst,
                             int R, int C, float scale) {
    __shared__ float tile[32][33];
    const float* s = src + (size_t)blockIdx.z * R * C;
    __hip_bfloat16* d = dst + (size_t)blockIdx.z * R * C;
    int c0 = blockIdx.x * 32;
    int r0 = blockIdx.y * 32;
    int tx = threadIdx.x;   // 0..31
    int ty = threadIdx.y;   // 0..7
    for (int i = 0; i < 4; ++i) {
        int r = r0 + ty + i * 8;
        tile[ty + i * 8][tx] = s[(size_t)r * C + c0 + tx];
    }
    __syncthreads();
    for (int i = 0; i < 4; ++i) {
        int c = c0 + ty + i * 8;
        d[(size_t)c * R + r0 + tx] = __float2bfloat16(tile[tx][ty + i * 8] * scale);
    }
}

// ---------------- GEMM: Y[m][n] = sum_c A[m][c] * BT[n][c]  (bf16 in, f32 acc) ----------------
template<int MODE>
__global__ __launch_bounds__(256) void gemm_kernel(
    const __hip_bfloat16* __restrict__ A,   // [M][1024]
    const __hip_bfloat16* __restrict__ BT,  // [N][1024]
    const float* __restrict__ bias,
    __hip_bfloat16* __restrict__ out_qkv,   // q base; k,v at +QKV_STRIDE
    float* __restrict__ out_f32)
{
    constexpr int K = Cn;
    __shared__ __hip_bfloat16 lA[128][40];
    __shared__ __hip_bfloat16 lB[128][40];
    const int m0 = blockIdx.x * 128;
    const int n0 = blockIdx.y * 128;
    const int tid = threadIdx.x;
    const int lane = tid & 63, wid = tid >> 6;
    const int wy = wid >> 1, wx = wid & 1;
    const int fr = lane & 15, fo = (lane >> 4) * 8;

    floatx4 acc[4][4] = {};

    const int srow = tid >> 2;         // 0..63
    const int scol = (tid & 3) * 8;    // 0,8,16,24

    for (int k0 = 0; k0 < K; k0 += 32) {
        for (int half = 0; half < 2; ++half) {
            int r = srow + half * 64;
            *(short8*)(&lA[r][scol]) = *(const short8*)(&A[(size_t)(m0 + r) * K + k0 + scol]);
            *(short8*)(&lB[r][scol]) = *(const short8*)(&BT[(size_t)(n0 + r) * K + k0 + scol]);
        }
        __syncthreads();
        short8 af[4], bf[4];
        for (int t = 0; t < 4; ++t) {
            af[t] = *(const short8*)(&lA[wy * 64 + t * 16 + fr][fo]);
            bf[t] = *(const short8*)(&lB[wx * 64 + t * 16 + fr][fo]);
        }
        for (int tm = 0; tm < 4; ++tm)
            for (int tn = 0; tn < 4; ++tn)
                acc[tm][tn] = __builtin_amdgcn_mfma_f32_16x16x32_bf16(af[tm], bf[tn], acc[tm][tn], 0, 0, 0);
        __syncthreads();
    }

    for (int tm = 0; tm < 4; ++tm) {
        int rbase = m0 + wy * 64 + tm * 16 + (lane >> 4) * 4;
        for (int tn = 0; tn < 4; ++tn) {
            int nc = n0 + wx * 64 + tn * 16 + fr;
            if (MODE == 0) {
                int w = nc >> 10, rem = nc & 1023, hh = rem >> 6, dd = rem & 63;
                if (w == 2) {
                    int b = rbase >> 11, t0 = rbase & 2047;
                    ushort4 pk;
                    pk.x = bfbits(acc[tm][tn][0]);
                    pk.y = bfbits(acc[tm][tn][1]);
                    pk.z = bfbits(acc[tm][tn][2]);
                    pk.w = bfbits(acc[tm][tn][3]);
                    *(ushort4*)(&out_qkv[2 * QKV_STRIDE +
                        ((size_t)((b * Hn + hh) * DHn + dd)) * Tn + t0]) = pk;
                } else {
                    for (int r = 0; r < 4; ++r) {
                        int m = rbase + r;
                        int b = m >> 11, t = m & 2047;
                        out_qkv[(size_t)w * QKV_STRIDE + (((size_t)(b * Hn + hh) * Tn + t) << 6) + dd] =
                            __float2bfloat16(acc[tm][tn][r]);
                    }
                }
            } else {
                float bs = bias[nc];
                for (int r = 0; r < 4; ++r) {
                    int m = rbase + r;
                    out_f32[(size_t)m * Cn + nc] = acc[tm][tn][r] + bs;
                }
            }
        }
    }
}

// ---------------- causal flash attention v4: balanced pair scheduling ----------------
// q,k: [B*H][T][DH] bf16;  vt: [B*H][DH][T] bf16;  ao: [B][T][H*DH] bf16
// Each block (x, bh) processes q-tiles {15-x, x}: 34 kv-steps for every block.
// Swapped-operand mfma(K,Q): softmax row is lane-local. P stays in registers.
// Scores arrive in log2 domain (0.125*log2e folded into Wq); exp2 + defer-max.
__global__ __launch_bounds__(256) void attn_kernel(
    const __hip_bfloat16* __restrict__ q,
    const __hip_bfloat16* __restrict__ k,
    const __hip_bfloat16* __restrict__ vt,
    __hip_bfloat16* __restrict__ ao)
{
    __shared__ __hip_bfloat16 lK[2][64][64];   // 16 KB, K tiles [s][d]
    __shared__ __hip_bfloat16 lV[2][64][64];   // 16 KB, V^T tiles [d][t]

    const int bh = blockIdx.y, b = bh >> 4, h = bh & 15;
    const int tid = threadIdx.x, lane = tid & 63, wid = tid >> 6;
    const int fr = lane & 15, g = lane >> 4;
    const size_t base = (size_t)bh * Tn * DHn;

    const int srow = tid >> 3;              // 0..31
    const int sc = tid & 7;                 // 16B chunk
    const int sxor = (sc * 16) ^ ((srow & 7) << 4);
    char* const k0p = (char*)&lK[0][0][0];
    char* const v0p = (char*)&lV[0][0][0];
    const int d0 = srow * 128 + sxor;
    const int d1 = (srow + 32) * 128 + sxor;    // (srow+32)&7 == srow&7
    const int rxor = (fr & 7) << 4;

    const int tiles[2] = { 15 - (int)blockIdx.x, (int)blockIdx.x };

    for (int tt = 0; tt < 2; ++tt) {
        const int qb0 = tiles[tt] * 128;
        const int q0 = qb0 + wid * 32;

        // Q fragments (B-operand: col=q=lane&15). 0.125*log2e folded into Wq.
        short8 aq[2][2];
#pragma unroll
        for (int rq = 0; rq < 2; ++rq)
#pragma unroll
            for (int kk = 0; kk < 2; ++kk)
                aq[rq][kk] = *(const short8*)(&q[base + (size_t)(q0 + rq * 16 + fr) * DHn + kk * 32 + g * 8]);

        float m_[2] = {-1e30f, -1e30f}, l_[2] = {0.f, 0.f};
        floatx4 o[2][4] = {};   // [rq][dg]: D[d][q], d = dg*16 + g*4 + r, q = lane&15

        const int nkv = qb0 / 64 + 2;

        short8 rk0, rk1, rv0, rv1;
        rk0 = *(const short8*)(&k[base + (size_t)srow * DHn + sc * 8]);
        rk1 = *(const short8*)(&k[base + (size_t)(srow + 32) * DHn + sc * 8]);
        rv0 = *(const short8*)(&vt[base + (size_t)srow * Tn + sc * 8]);
        rv1 = *(const short8*)(&vt[base + (size_t)(srow + 32) * Tn + sc * 8]);
        *(short8*)(k0p + d0) = rk0;
        *(short8*)(k0p + d1) = rk1;
        *(short8*)(v0p + d0) = rv0;
        *(short8*)(v0p + d1) = rv1;
        __syncthreads();

        for (int j = 0; j < nkv; ++j) {
            const int kv0 = j * 64;
            const int cur = j & 1;
            const char* lkc = k0p + cur * 8192;
            const char* lvc = v0p + cur * 8192;
            const bool pfch = (j + 1 < nkv);
            if (pfch) {
                const int nv0 = kv0 + 64;
                rk0 = *(const short8*)(&k[base + (size_t)(nv0 + srow) * DHn + sc * 8]);
                rk1 = *(const short8*)(&k[base + (size_t)(nv0 + srow + 32) * DHn + sc * 8]);
                rv0 = *(const short8*)(&vt[base + (size_t)srow * Tn + nv0 + sc * 8]);
                rv1 = *(const short8*)(&vt[base + (size_t)(srow + 32) * Tn + nv0 + sc * 8]);
            }

            if (kv0 < q0 + 32) {
                // ---- QK^T (swapped): s[rq][cg] row k = cg*16+g*4+r, col q = fr ----
                floatx4 s[2][4] = {};
                __builtin_amdgcn_s_setprio(1);
#pragma unroll
                for (int kk = 0; kk < 2; ++kk)
#pragma unroll
                    for (int cg = 0; cg < 4; ++cg) {
                        short8 kf = *(const short8*)(lkc + (cg * 16 + fr) * 128 + ((g * 16 + kk * 64) ^ rxor));
                        s[0][cg] = __builtin_amdgcn_mfma_f32_16x16x32_bf16(kf, aq[0][kk], s[0][cg], 0, 0, 0);
                        s[1][cg] = __builtin_amdgcn_mfma_f32_16x16x32_bf16(kf, aq[1][kk], s[1][cg], 0, 0, 0);
                    }
                __builtin_amdgcn_s_setprio(0);

                // ---- causal mask (diagonal region only) ----
                if (kv0 + 64 > q0) {
#pragma unroll
                    for (int rq = 0; rq < 2; ++rq) {
                        int qg = q0 + rq * 16 + fr;
#pragma unroll
                        for (int cg = 0; cg < 4; ++cg) {
                            int kg = kv0 + cg * 16 + g * 4;
#pragma unroll
                            for (int r = 0; r < 4; ++r)
                                if (kg + r > qg) s[rq][cg][r] = -1e30f;
                        }
                    }
                }

                // ---- lane-local online softmax (log2 domain, defer-max) ----
                short8 pb[2][2];
#pragma unroll
                for (int rq = 0; rq < 2; ++rq) {
                    float mx = fmaxf(
                        fmaxf(fmaxf(fmaxf(s[rq][0][0], s[rq][0][1]), fmaxf(s[rq][0][2], s[rq][0][3])),
                              fmaxf(fmaxf(s[rq][1][0], s[rq][1][1]), fmaxf(s[rq][1][2], s[rq][1][3]))),
                        fmaxf(fmaxf(fmaxf(s[rq][2][0], s[rq][2][1]), fmaxf(s[rq][2][2], s[rq][2][3])),
                              fmaxf(fmaxf(s[rq][3][0], s[rq][3][1]), fmaxf(s[rq][3][2], s[rq][3][3]))));
                    mx = fmaxf(mx, __shfl_xor(mx, 16));
                    mx = fmaxf(mx, __shfl_xor(mx, 32));
                    if (!__all(mx <= m_[rq] + 8.0f)) {
                        float nm = fmaxf(m_[rq], mx);
                        float al = __builtin_amdgcn_exp2f(m_[rq] - nm);
                        m_[rq] = nm;
                        l_[rq] *= al;
#pragma unroll
                        for (int dg = 0; dg < 4; ++dg) o[rq][dg] *= al;
                    }
                    const float mm = m_[rq];
                    float ls = 0.f;
#pragma unroll
                    for (int cg = 0; cg < 4; ++cg)
#pragma unroll
                        for (int r = 0; r < 4; ++r) {
                            float p = __builtin_amdgcn_exp2f(s[rq][cg][r] - mm);
                            s[rq][cg][r] = p;
                            ls += p;
                        }
                    l_[rq] += ls;
                    // pack P: B-frag slot j ↔ k = kt*32 + (j<4 ? 4g+j : 16+4g+(j-4))
#pragma unroll
                    for (int kt = 0; kt < 2; ++kt) {
                        short8 pk;
#pragma unroll
                        for (int r = 0; r < 4; ++r) {
                            pk[r]     = (short)bfbits(s[rq][2 * kt][r]);
                            pk[r + 4] = (short)bfbits(s[rq][2 * kt + 1][r]);
                        }
                        pb[rq][kt] = pk;
                    }
                }

                // ---- PV (swapped): o[d][q] += V^T[d][k_perm] * P[k_perm][q] ----
                __builtin_amdgcn_s_setprio(1);
#pragma unroll
                for (int kt = 0; kt < 2; ++kt)
#pragma unroll
                    for (int dg = 0; dg < 4; ++dg) {
                        const int vrow = (dg * 16 + fr) * 128;
                        s4v lo = *(const s4v*)(lvc + vrow + ((kt * 64 + 8 * g) ^ rxor));
                        s4v hi = *(const s4v*)(lvc + vrow + ((kt * 64 + 32 + 8 * g) ^ rxor));
                        short8 vf;
                        vf[0] = lo[0]; vf[1] = lo[1]; vf[2] = lo[2]; vf[3] = lo[3];
                        vf[4] = hi[0]; vf[5] = hi[1]; vf[6] = hi[2]; vf[7] = hi[3];
                        o[0][dg] = __builtin_amdgcn_mfma_f32_16x16x32_bf16(vf, pb[0][kt], o[0][dg], 0, 0, 0);
                        o[1][dg] = __builtin_amdgcn_mfma_f32_16x16x32_bf16(vf, pb[1][kt], o[1][dg], 0, 0, 0);
                    }
                __builtin_amdgcn_s_setprio(0);
            }

            if (pfch) {
                char* nk = k0p + (cur ^ 1) * 8192;
                char* nv = v0p + (cur ^ 1) * 8192;
                *(short8*)(nk + d0) = rk0;
                *(short8*)(nk + d1) = rk1;
                *(short8*)(nv + d0) = rv0;
                *(short8*)(nv + d1) = rv1;
            }
            __syncthreads();
        }

        // ---- epilogue: reduce l, normalize, transpose via LDS scratch, coalesced store ----
        float inv_[2];
#pragma unroll
        for (int rq = 0; rq < 2; ++rq) {
            float lv = l_[rq];
            lv += __shfl_xor(lv, 16);
            lv += __shfl_xor(lv, 32);
            inv_[rq] = 1.0f / lv;
        }
        char* myscr = k0p + wid * 4096;   // per-wave 16x64 f32 region (reuses lK)
        const int rr = lane >> 2, cc = lane & 3;
#pragma unroll
        for (int rq = 0; rq < 2; ++rq) {
#pragma unroll
            for (int dg = 0; dg < 4; ++dg)
#pragma unroll
                for (int r = 0; r < 4; ++r) {
                    int d = dg * 16 + g * 4 + r;
                    *(float*)(myscr + fr * 256 + ((d * 4) ^ ((fr & 7) << 4))) = o[rq][dg][r] * inv_[rq];
                }
            asm volatile("s_waitcnt lgkmcnt(0)" ::: "memory");
            float4 f0 = *(const float4*)(myscr + rr * 256 + ((cc * 64 + 0) ^ ((rr & 7) << 4)));
            float4 f1 = *(const float4*)(myscr + rr * 256 + ((cc * 64 + 16) ^ ((rr & 7) << 4)));
            float4 f2 = *(const float4*)(myscr + rr * 256 + ((cc * 64 + 32) ^ ((rr & 7) << 4)));
            float4 f3 = *(const float4*)(myscr + rr * 256 + ((cc * 64 + 48) ^ ((rr & 7) << 4)));
            short8 pk0, pk1;
            pk0[0] = (short)bfbits(f0.x); pk0[1] = (short)bfbits(f0.y);
            pk0[2] = (short)bfbits(f0.z); pk0[3] = (short)bfbits(f0.w);
            pk0[4] = (short)bfbits(f1.x); pk0[5] = (short)bfbits(f1.y);
            pk0[6] = (short)bfbits(f1.z); pk0[7] = (short)bfbits(f1.w);
            pk1[0] = (short)bfbits(f2.x); pk1[1] = (short)bfbits(f2.y);
            pk1[2] = (short)bfbits(f2.z); pk1[3] = (short)bfbits(f2.w);
            pk1[4] = (short)bfbits(f3.x); pk1[5] = (short)bfbits(f3.y);
            pk1[6] = (short)bfbits(f3.z); pk1[7] = (short)bfbits(f3.w);
            size_t orow = ((size_t)(b * Tn + q0 + rq * 16 + rr)) * Cn + h * 64 + cc * 16;
            *(short8*)(&ao[orow]) = pk0;
            *(short8*)(&ao[orow + 8]) = pk1;
            asm volatile("s_waitcnt lgkmcnt(0)" ::: "memory");
        }
        __syncthreads();   // protect LDS scratch before next tile's staging
    }
}

extern "C" void kernel_launch(void* const* d_in, const int* in_sizes, int n_in,
                              void* d_out, int out_size, void* d_ws, size_t ws_size,
                              hipStream_t stream) {
    const float* x  = (const float*)d_in[0];
    const float* Wq = (const float*)d_in[1];
    const float* Wk = (const float*)d_in[2];
    const float* Wv = (const float*)d_in[3];
    const float* Wo = (const float*)d_in[4];
    const float* bo = (const float*)d_in[5];
    float* out = (float*)d_out;

    char* ws = (char*)d_ws;
    __hip_bfloat16* xb  = (__hip_bfloat16*)(ws);                    // [8192][1024]        16 MB
    __hip_bfloat16* wT  = (__hip_bfloat16*)(ws + 16777216);         // [3][1024][1024]      6 MB
    __hip_bfloat16* woT = (__hip_bfloat16*)(ws + 23068672);         // [1024][1024]         2 MB
    __hip_bfloat16* qb  = (__hip_bfloat16*)(ws + 25165824);         // q,k,v each 16 MB
    __hip_bfloat16* ao  = (__hip_bfloat16*)(ws + 75497472);         // [8192][1024]        16 MB

    // x -> bf16
    conv_kernel<<<(Mtot * Cn / 4 + 255) / 256, 256, 0, stream>>>(
        (const float4*)x, (ushort4*)xb, Mtot * Cn / 4);
    // weights -> transposed bf16 (Wq carries 1/sqrt(DH) * log2(e) for exp2-domain softmax)
    tconv_kernel<<<dim3(2, 32, 16), dim3(32, 8), 0, stream>>>(Wq, wT + 0 * 1048576, Cn, DHn, 0.125f * 1.44269504088896f);
    tconv_kernel<<<dim3(2, 32, 16), dim3(32, 8), 0, stream>>>(Wk, wT + 1 * 1048576, Cn, DHn, 1.0f);
    tconv_kernel<<<dim3(2, 32, 16), dim3(32, 8), 0, stream>>>(Wv, wT + 2 * 1048576, Cn, DHn, 1.0f);
    tconv_kernel<<<dim3(32, 32, 1), dim3(32, 8), 0, stream>>>(Wo, woT, Cn, Cn, 1.0f);

    // QKV projection: M=8192, N=3072 (V stored transposed)
    gemm_kernel<0><<<dim3(Mtot / 128, 3072 / 128), 256, 0, stream>>>(
        xb, wT, nullptr, qb, nullptr);

    // causal flash attention (balanced pairs: 8 pair-blocks x 64 bh)
    attn_kernel<<<dim3(8, Bn * Hn), 256, 0, stream>>>(
        qb, qb + QKV_STRIDE, qb + 2 * QKV_STRIDE, ao);

    // output projection: M=8192, N=1024, +bias, f32 out
    gemm_kernel<1><<<dim3(Mtot / 128, Cn / 128), 256, 0, stream>>>(
        ao, woT, bo, nullptr, out);
}